// Round 1
// baseline (354.686 us; speedup 1.0000x reference)
//
#include <hip/hip_runtime.h>

// Tricubic B-spline evaluation, p=3, n_ctrl=32 per dim, open-uniform knots.
// queries: [Q,3] f32 in [0,1); control_points: [32^3, 3] f32; out: [Q,3] f32.

#define P 3
#define NCTRL 32
#define NSEG 29  // n_ctrl - p segments in [0,1]

__device__ __forceinline__ float knotv(int k) {
    // knots[0..3]=0, knots[4..31]=(k-3)/29, knots[32..35]=1 — clamp trick
    float t = (float)(k - P) * (1.0f / (float)NSEG);
    return fminf(fmaxf(t, 0.0f), 1.0f);
}

__device__ __forceinline__ void basis1d(float u, int& i0, float N[4]) {
    int t = (int)floorf(u * (float)NSEG);
    t = min(max(t, 0), NSEG - 1);
    int s = t + P;  // span in [3, 31]
    float left[P + 1], right[P + 1];  // index 0 unused
#pragma unroll
    for (int j = 1; j <= P; ++j) {
        left[j]  = u - knotv(s + 1 - j);
        right[j] = knotv(s + j) - u;
    }
    N[0] = 1.0f;
#pragma unroll
    for (int j = 1; j <= P; ++j) {
        float saved = 0.0f;
#pragma unroll
        for (int r = 0; r < j; ++r) {
            float temp = N[r] / (right[r + 1] + left[j - r]);
            N[r] = saved + right[r + 1] * temp;
            saved = left[j - r] * temp;
        }
        N[j] = saved;
    }
    i0 = s - P;
}

__global__ void __launch_bounds__(256) repack_cp(const float* __restrict__ cp,
                                                float4* __restrict__ cp4, int n) {
    int i = blockIdx.x * blockDim.x + threadIdx.x;
    if (i < n) {
        cp4[i] = make_float4(cp[3 * i + 0], cp[3 * i + 1], cp[3 * i + 2], 0.0f);
    }
}

__global__ void __launch_bounds__(256) spline_eval(const float* __restrict__ q,
                                                   const float4* __restrict__ cp4,
                                                   float* __restrict__ out, int Q) {
    int idx = blockIdx.x * blockDim.x + threadIdx.x;
    if (idx >= Q) return;
    float ux = q[3 * idx + 0];
    float uy = q[3 * idx + 1];
    float uz = q[3 * idx + 2];
    int ix0, iy0, iz0;
    float Bx[4], By[4], Bz[4];
    basis1d(ux, ix0, Bx);
    basis1d(uy, iy0, By);
    basis1d(uz, iz0, Bz);
    float ax = 0.f, ay = 0.f, az = 0.f;
#pragma unroll
    for (int k = 0; k < 4; ++k) {
#pragma unroll
        for (int j = 0; j < 4; ++j) {
            float w = Bz[k] * By[j];
            int base = ((iz0 + k) * NCTRL + (iy0 + j)) * NCTRL + ix0;
#pragma unroll
            for (int i = 0; i < 4; ++i) {
                float4 c = cp4[base + i];
                float wi = w * Bx[i];
                ax = fmaf(wi, c.x, ax);
                ay = fmaf(wi, c.y, ay);
                az = fmaf(wi, c.z, az);
            }
        }
    }
    out[3 * idx + 0] = ax;
    out[3 * idx + 1] = ay;
    out[3 * idx + 2] = az;
}

// Fallback if workspace is too small: read [n,3] layout directly.
__global__ void __launch_bounds__(256) spline_eval_direct(const float* __restrict__ q,
                                                          const float* __restrict__ cp,
                                                          float* __restrict__ out, int Q) {
    int idx = blockIdx.x * blockDim.x + threadIdx.x;
    if (idx >= Q) return;
    float ux = q[3 * idx + 0];
    float uy = q[3 * idx + 1];
    float uz = q[3 * idx + 2];
    int ix0, iy0, iz0;
    float Bx[4], By[4], Bz[4];
    basis1d(ux, ix0, Bx);
    basis1d(uy, iy0, By);
    basis1d(uz, iz0, Bz);
    float ax = 0.f, ay = 0.f, az = 0.f;
#pragma unroll
    for (int k = 0; k < 4; ++k) {
#pragma unroll
        for (int j = 0; j < 4; ++j) {
            float w = Bz[k] * By[j];
            int base = ((iz0 + k) * NCTRL + (iy0 + j)) * NCTRL + ix0;
#pragma unroll
            for (int i = 0; i < 4; ++i) {
                float wi = w * Bx[i];
                ax = fmaf(wi, cp[3 * (base + i) + 0], ax);
                ay = fmaf(wi, cp[3 * (base + i) + 1], ay);
                az = fmaf(wi, cp[3 * (base + i) + 2], az);
            }
        }
    }
    out[3 * idx + 0] = ax;
    out[3 * idx + 1] = ay;
    out[3 * idx + 2] = az;
}

extern "C" void kernel_launch(void* const* d_in, const int* in_sizes, int n_in,
                              void* d_out, int out_size, void* d_ws, size_t ws_size,
                              hipStream_t stream) {
    const float* q  = (const float*)d_in[0];
    const float* cp = (const float*)d_in[1];
    float* out = (float*)d_out;
    int Q   = in_sizes[0] / 3;
    int ncp = in_sizes[1] / 3;  // 32768

    if (ws_size >= (size_t)ncp * sizeof(float4)) {
        float4* cp4 = (float4*)d_ws;
        repack_cp<<<(ncp + 255) / 256, 256, 0, stream>>>(cp, cp4, ncp);
        spline_eval<<<(Q + 255) / 256, 256, 0, stream>>>(q, cp4, out, Q);
    } else {
        spline_eval_direct<<<(Q + 255) / 256, 256, 0, stream>>>(q, cp, out, Q);
    }
}

// Round 2
// 200.982 us; speedup vs baseline: 1.7648x; 1.7648x over previous
//
#include <hip/hip_runtime.h>

// Tricubic B-spline evaluation, p=3, n_ctrl=32 per dim, open-uniform knots.
// queries: [Q,3] f32 in [0,1); control_points: [32^3, 3] f32; out: [Q,3] f32.
//
// Strategy: repack control points into per-(z,y,ix0) aligned 64B "rows"
// (4 consecutive x control points as 4 x float4), then evaluate with 4
// cooperating lanes per query so each row read is a single coalesced
// 64B cache line (1 TCP transaction instead of 4 divergent ones).

#define P 3
#define NCTRL 32
#define NSEG 29  // n_ctrl - p segments in [0,1]; also #valid ix0 values

__device__ __forceinline__ float knotv(int k) {
    // knots[0..3]=0, knots[4..31]=(k-3)/29, knots[32..35]=1 — clamp trick
    float t = (float)(k - P) * (1.0f / (float)NSEG);
    return fminf(fmaxf(t, 0.0f), 1.0f);
}

__device__ __forceinline__ void basis1d(float u, int& i0, float N[4]) {
    int t = (int)floorf(u * (float)NSEG);
    t = min(max(t, 0), NSEG - 1);
    int s = t + P;  // span in [3, 31]
    float left[P + 1], right[P + 1];  // index 0 unused
#pragma unroll
    for (int j = 1; j <= P; ++j) {
        left[j]  = u - knotv(s + 1 - j);
        right[j] = knotv(s + j) - u;
    }
    N[0] = 1.0f;
#pragma unroll
    for (int j = 1; j <= P; ++j) {
        float saved = 0.0f;
#pragma unroll
        for (int r = 0; r < j; ++r) {
            float temp = N[r] / (right[r + 1] + left[j - r]);
            N[r] = saved + right[r + 1] * temp;
            saved = left[j - r] * temp;
        }
        N[j] = saved;
    }
    i0 = s - P;
}

// Repack: rows[((z*32+y)*29 + s)*4 + c] = cp[(z*32+y)*32 + s + c] as float4.
// Each row (4 float4 = 64B) is 64B-aligned -> one cache line per row read.
__global__ void __launch_bounds__(256) repack_rows(const float* __restrict__ cp,
                                                   float4* __restrict__ rows,
                                                   int nelem) {
    int i = blockIdx.x * blockDim.x + threadIdx.x;
    if (i >= nelem) return;
    int row = i >> 2, c = i & 3;
    int z   = row / (NCTRL * NSEG);
    int rem = row % (NCTRL * NSEG);
    int y   = rem / NSEG;
    int s   = rem % NSEG;
    int x   = s + c;
    int src = (z * NCTRL + y) * NCTRL + x;
    rows[i] = make_float4(cp[3 * src + 0], cp[3 * src + 1], cp[3 * src + 2], 0.0f);
}

// 4 lanes per query: lane c handles x-offset c of every row; quad shuffle-reduce.
__global__ void __launch_bounds__(256) spline_eval_quad(const float* __restrict__ q,
                                                        const float4* __restrict__ rows,
                                                        float* __restrict__ out, int Q) {
    int t = blockIdx.x * blockDim.x + threadIdx.x;
    int g = t >> 2;
    int c = t & 3;
    if (g >= Q) return;
    float ux = q[3 * g + 0];
    float uy = q[3 * g + 1];
    float uz = q[3 * g + 2];
    int ix0, iy0, iz0;
    float Bx[4], By[4], Bz[4];
    basis1d(ux, ix0, Bx);
    basis1d(uy, iy0, By);
    basis1d(uz, iz0, Bz);
    float bxc = Bx[c];
    float ax = 0.f, ay = 0.f, az = 0.f;
#pragma unroll
    for (int k = 0; k < 4; ++k) {
#pragma unroll
        for (int j = 0; j < 4; ++j) {
            int row = ((iz0 + k) * NCTRL + (iy0 + j)) * NSEG + ix0;
            float4 cv = rows[row * 4 + c];
            float w = Bz[k] * By[j] * bxc;
            ax = fmaf(w, cv.x, ax);
            ay = fmaf(w, cv.y, ay);
            az = fmaf(w, cv.z, az);
        }
    }
    // quad reduction (lanes {4m..4m+3})
    ax += __shfl_xor(ax, 1); ax += __shfl_xor(ax, 2);
    ay += __shfl_xor(ay, 1); ay += __shfl_xor(ay, 2);
    az += __shfl_xor(az, 1); az += __shfl_xor(az, 2);
    float val = (c == 0) ? ax : (c == 1) ? ay : az;
    if (c < 3) out[3 * g + c] = val;
}

// Fallback if workspace is too small: direct [n,3]-layout gather per thread.
__global__ void __launch_bounds__(256) spline_eval_direct(const float* __restrict__ q,
                                                          const float* __restrict__ cp,
                                                          float* __restrict__ out, int Q) {
    int idx = blockIdx.x * blockDim.x + threadIdx.x;
    if (idx >= Q) return;
    float ux = q[3 * idx + 0];
    float uy = q[3 * idx + 1];
    float uz = q[3 * idx + 2];
    int ix0, iy0, iz0;
    float Bx[4], By[4], Bz[4];
    basis1d(ux, ix0, Bx);
    basis1d(uy, iy0, By);
    basis1d(uz, iz0, Bz);
    float ax = 0.f, ay = 0.f, az = 0.f;
#pragma unroll
    for (int k = 0; k < 4; ++k) {
#pragma unroll
        for (int j = 0; j < 4; ++j) {
            float w = Bz[k] * By[j];
            int base = ((iz0 + k) * NCTRL + (iy0 + j)) * NCTRL + ix0;
#pragma unroll
            for (int i = 0; i < 4; ++i) {
                float wi = w * Bx[i];
                ax = fmaf(wi, cp[3 * (base + i) + 0], ax);
                ay = fmaf(wi, cp[3 * (base + i) + 1], ay);
                az = fmaf(wi, cp[3 * (base + i) + 2], az);
            }
        }
    }
    out[3 * idx + 0] = ax;
    out[3 * idx + 1] = ay;
    out[3 * idx + 2] = az;
}

extern "C" void kernel_launch(void* const* d_in, const int* in_sizes, int n_in,
                              void* d_out, int out_size, void* d_ws, size_t ws_size,
                              hipStream_t stream) {
    const float* q  = (const float*)d_in[0];
    const float* cp = (const float*)d_in[1];
    float* out = (float*)d_out;
    int Q = in_sizes[0] / 3;

    const int nrows = NCTRL * NCTRL * NSEG;   // 29696
    const int nelem = nrows * 4;              // 118784 float4 = 1.86 MB
    if (ws_size >= (size_t)nelem * sizeof(float4)) {
        float4* rows = (float4*)d_ws;
        repack_rows<<<(nelem + 255) / 256, 256, 0, stream>>>(cp, rows, nelem);
        long long nthreads = 4LL * Q;
        spline_eval_quad<<<(int)((nthreads + 255) / 256), 256, 0, stream>>>(q, rows, out, Q);
    } else {
        spline_eval_direct<<<(Q + 255) / 256, 256, 0, stream>>>(q, cp, out, Q);
    }
}

// Round 3
// 199.808 us; speedup vs baseline: 1.7751x; 1.0059x over previous
//
#include <hip/hip_runtime.h>

// Tricubic B-spline evaluation, p=3, n_ctrl=32 per dim, open-uniform knots.
// queries: [Q,3] f32 in [0,1); control_points: [32^3, 3] f32; out: [Q,3] f32.
//
// Round 2: division-free Cox-de Boor in integer knot units (denominators are
// {1,2,3} -> single v_rcp_f32), pre-multiplied Bz*By weights, Bx folded in
// after the gather loop. Quad-cooperative 64B-row gather unchanged.

#define P 3
#define NCTRL 32
#define NSEG 29  // n_ctrl - p segments in [0,1]; also #valid ix0 values

// Division-free basis: work in knot units (knots at clamp(k,0,29), U=29u).
// Cox-de Boor is scale-invariant, so N values match the reference.
__device__ __forceinline__ void basis1d(float u, int& i0, float N[4]) {
    float U = u * (float)NSEG;
    float ft = floorf(U);
    ft = fminf(fmaxf(ft, 0.0f), (float)(NSEG - 1));
    float x  = U - ft;          // left[1]
    float r1 = 1.0f - x;        // right[1]
    // clamped knot positions (knot units)
    float km1 = fmaxf(ft - 1.0f, 0.0f);           // K(t-1)
    float km2 = fmaxf(ft - 2.0f, 0.0f);           // K(t-2)
    float kp2 = fminf(ft + 2.0f, (float)NSEG);    // K(t+2)
    float kp3 = fminf(ft + 3.0f, (float)NSEG);    // K(t+3)
    float l2 = U - km1;         // left[2]
    float l3 = U - km2;         // left[3]
    float r2 = kp2 - U;         // right[2]
    float r3 = kp3 - U;         // right[3]
    // j=1 (denominator exactly 1): N = {1-x, x}
    float N0 = r1, N1 = x;
    // j=2: dens = {K(t+1)-K(t-1), K(t+2)-K(t)} in {1,2}
    float rcp20 = __builtin_amdgcn_rcpf(ft + 1.0f - km1);
    float rcp21 = __builtin_amdgcn_rcpf(kp2 - ft);
    float temp  = N0 * rcp20;
    N0 = r1 * temp;
    float saved = l2 * temp;
    temp = N1 * rcp21;
    N1 = saved + r2 * temp;
    float N2 = x * temp;
    // j=3: dens = {K(t+1)-K(t-2), K(t+2)-K(t-1), K(t+3)-K(t)} in {1,2,3}
    float rcp30 = __builtin_amdgcn_rcpf(ft + 1.0f - km2);
    float rcp31 = __builtin_amdgcn_rcpf(kp2 - km1);
    float rcp32 = __builtin_amdgcn_rcpf(kp3 - ft);
    temp = N0 * rcp30;
    N0 = r1 * temp;
    saved = l3 * temp;
    temp = N1 * rcp31;
    N1 = saved + r2 * temp;
    saved = l2 * temp;
    temp = N2 * rcp32;
    N2 = saved + r3 * temp;
    float N3 = x * temp;
    N[0] = N0; N[1] = N1; N[2] = N2; N[3] = N3;
    i0 = (int)ft;   // = span - P
}

// Repack: rows[((z*32+y)*29 + s)*4 + c] = cp[(z*32+y)*32 + s + c] as float4.
// Each row (4 float4 = 64B) is 64B-aligned -> one cache line per row read.
__global__ void __launch_bounds__(256) repack_rows(const float* __restrict__ cp,
                                                   float4* __restrict__ rows,
                                                   int nelem) {
    int i = blockIdx.x * blockDim.x + threadIdx.x;
    if (i >= nelem) return;
    int row = i >> 2, c = i & 3;
    int z   = row / (NCTRL * NSEG);
    int rem = row % (NCTRL * NSEG);
    int y   = rem / NSEG;
    int s   = rem % NSEG;
    int x   = s + c;
    int src = (z * NCTRL + y) * NCTRL + x;
    rows[i] = make_float4(cp[3 * src + 0], cp[3 * src + 1], cp[3 * src + 2], 0.0f);
}

// 4 lanes per query: lane c handles x-offset c of every row; quad shuffle-reduce.
__global__ void __launch_bounds__(256) spline_eval_quad(const float* __restrict__ q,
                                                        const float4* __restrict__ rows,
                                                        float* __restrict__ out, int Q) {
    int t = blockIdx.x * blockDim.x + threadIdx.x;
    int g = t >> 2;
    int c = t & 3;
    if (g >= Q) return;
    float ux = q[3 * g + 0];
    float uy = q[3 * g + 1];
    float uz = q[3 * g + 2];
    int ix0, iy0, iz0;
    float Bx[4], By[4], Bz[4];
    basis1d(ux, ix0, Bx);
    basis1d(uy, iy0, By);
    basis1d(uz, iz0, Bz);
    // premultiplied z*y weights
    float wzy[16];
#pragma unroll
    for (int k = 0; k < 4; ++k)
#pragma unroll
        for (int j = 0; j < 4; ++j)
            wzy[k * 4 + j] = Bz[k] * By[j];

    const int base = ((iz0 * NCTRL) + iy0) * NSEG + ix0;  // row index of (k=0,j=0)
    const float4* rp = rows + (size_t)base * 4 + c;

    float ax = 0.f, ay = 0.f, az = 0.f;
#pragma unroll
    for (int k = 0; k < 4; ++k) {
#pragma unroll
        for (int j = 0; j < 4; ++j) {
            float4 cv = rp[(k * NCTRL + j) * NSEG * 4];
            float w = wzy[k * 4 + j];
            ax = fmaf(w, cv.x, ax);
            ay = fmaf(w, cv.y, ay);
            az = fmaf(w, cv.z, az);
        }
    }
    // fold this lane's Bx once, then quad-reduce
    float bxc = Bx[c];
    ax *= bxc; ay *= bxc; az *= bxc;
    ax += __shfl_xor(ax, 1); ax += __shfl_xor(ax, 2);
    ay += __shfl_xor(ay, 1); ay += __shfl_xor(ay, 2);
    az += __shfl_xor(az, 1); az += __shfl_xor(az, 2);
    float val = (c == 0) ? ax : (c == 1) ? ay : az;
    if (c < 3) out[3 * g + c] = val;
}

// Fallback if workspace is too small: direct [n,3]-layout gather per thread.
__global__ void __launch_bounds__(256) spline_eval_direct(const float* __restrict__ q,
                                                          const float* __restrict__ cp,
                                                          float* __restrict__ out, int Q) {
    int idx = blockIdx.x * blockDim.x + threadIdx.x;
    if (idx >= Q) return;
    int ix0, iy0, iz0;
    float Bx[4], By[4], Bz[4];
    basis1d(q[3 * idx + 0], ix0, Bx);
    basis1d(q[3 * idx + 1], iy0, By);
    basis1d(q[3 * idx + 2], iz0, Bz);
    float ax = 0.f, ay = 0.f, az = 0.f;
#pragma unroll
    for (int k = 0; k < 4; ++k) {
#pragma unroll
        for (int j = 0; j < 4; ++j) {
            float w = Bz[k] * By[j];
            int base = ((iz0 + k) * NCTRL + (iy0 + j)) * NCTRL + ix0;
#pragma unroll
            for (int i = 0; i < 4; ++i) {
                float wi = w * Bx[i];
                ax = fmaf(wi, cp[3 * (base + i) + 0], ax);
                ay = fmaf(wi, cp[3 * (base + i) + 1], ay);
                az = fmaf(wi, cp[3 * (base + i) + 2], az);
            }
        }
    }
    out[3 * idx + 0] = ax;
    out[3 * idx + 1] = ay;
    out[3 * idx + 2] = az;
}

extern "C" void kernel_launch(void* const* d_in, const int* in_sizes, int n_in,
                              void* d_out, int out_size, void* d_ws, size_t ws_size,
                              hipStream_t stream) {
    const float* q  = (const float*)d_in[0];
    const float* cp = (const float*)d_in[1];
    float* out = (float*)d_out;
    int Q = in_sizes[0] / 3;

    const int nrows = NCTRL * NCTRL * NSEG;   // 29696
    const int nelem = nrows * 4;              // 118784 float4 = 1.86 MB
    if (ws_size >= (size_t)nelem * sizeof(float4)) {
        float4* rows = (float4*)d_ws;
        repack_rows<<<(nelem + 255) / 256, 256, 0, stream>>>(cp, rows, nelem);
        long long nthreads = 4LL * Q;
        spline_eval_quad<<<(int)((nthreads + 255) / 256), 256, 0, stream>>>(q, rows, out, Q);
    } else {
        spline_eval_direct<<<(Q + 255) / 256, 256, 0, stream>>>(q, cp, out, Q);
    }
}